// Round 1
// baseline (822.980 us; speedup 1.0000x reference)
//
#include <hip/hip_runtime.h>

constexpr int NODES = 100000;

__global__ __launch_bounds__(256) void edge_scatter(
    const float* __restrict__ emb,   // [64][16]
    const float* __restrict__ cf,    // [E][16]
    const float* __restrict__ wts,   // [E]
    const int*   __restrict__ idx,   // [E]
    float* __restrict__ num,         // [NODES][64] (accumulated in d_out)
    float* __restrict__ den,         // [NODES]     (in d_ws)
    int E)
{
    const int lane = threadIdx.x & 63;

    // lane u holds embedding row u (16 floats, 16 VGPRs)
    float er[16];
    #pragma unroll
    for (int f = 0; f < 16; ++f) er[f] = emb[lane * 16 + f];

    // wave-uniform edge cursor -> scalar loads for cf/w/idx
    int wid = __builtin_amdgcn_readfirstlane(
        (int)((blockIdx.x * blockDim.x + threadIdx.x) >> 6));
    int nw = (gridDim.x * blockDim.x) >> 6;

    for (int e0 = wid * 4; e0 < E; e0 += nw * 4) {
        if (e0 + 3 < E) {
            float acc[4];
            #pragma unroll
            for (int k = 0; k < 4; ++k) {
                const float* c = cf + (size_t)(e0 + k) * 16;
                float a = 0.f;
                #pragma unroll
                for (int f = 0; f < 16; ++f) a = fmaf(c[f], er[f], a);
                acc[k] = a;
            }
            float w0 = wts[e0 + 0], w1 = wts[e0 + 1];
            float w2 = wts[e0 + 2], w3 = wts[e0 + 3];
            int n0 = idx[e0 + 0], n1 = idx[e0 + 1];
            int n2 = idx[e0 + 2], n3 = idx[e0 + 3];

            unsafeAtomicAdd(num + (size_t)n0 * 64 + lane, fmaxf(acc[0], 0.f) * w0);
            unsafeAtomicAdd(num + (size_t)n1 * 64 + lane, fmaxf(acc[1], 0.f) * w1);
            unsafeAtomicAdd(num + (size_t)n2 * 64 + lane, fmaxf(acc[2], 0.f) * w2);
            unsafeAtomicAdd(num + (size_t)n3 * 64 + lane, fmaxf(acc[3], 0.f) * w3);
            if (lane == 0) {
                unsafeAtomicAdd(den + n0, w0);
                unsafeAtomicAdd(den + n1, w1);
                unsafeAtomicAdd(den + n2, w2);
                unsafeAtomicAdd(den + n3, w3);
            }
        } else {
            for (int e = e0; e < E; ++e) {
                const float* c = cf + (size_t)e * 16;
                float a = 0.f;
                #pragma unroll
                for (int f = 0; f < 16; ++f) a = fmaf(c[f], er[f], a);
                float wv = wts[e];
                int   n  = idx[e];
                unsafeAtomicAdd(num + (size_t)n * 64 + lane, fmaxf(a, 0.f) * wv);
                if (lane == 0) unsafeAtomicAdd(den + n, wv);
            }
        }
    }
}

__global__ __launch_bounds__(256) void divide_kernel(
    float* __restrict__ out, const float* __restrict__ den, int nvec)
{
    int i = blockIdx.x * blockDim.x + threadIdx.x;
    int stride = gridDim.x * blockDim.x;
    float4* o4 = reinterpret_cast<float4*>(out);
    for (; i < nvec; i += stride) {
        float4 v = o4[i];
        float d = den[i >> 4];   // 16 float4 per node
        v.x /= d; v.y /= d; v.z /= d; v.w /= d;
        o4[i] = v;
    }
}

extern "C" void kernel_launch(void* const* d_in, const int* in_sizes, int n_in,
                              void* d_out, int out_size, void* d_ws, size_t ws_size,
                              hipStream_t stream)
{
    const float* emb = (const float*)d_in[0];   // (64,16)
    const float* cf  = (const float*)d_in[1];   // (E,16)
    const float* wts = (const float*)d_in[2];   // (E,)
    const int*   idx = (const int*)d_in[3];     // (E,)
    int E = in_sizes[2];

    float* out = (float*)d_out;                 // num accumulator, then result
    float* den = (float*)d_ws;                  // NODES floats

    hipMemsetAsync(d_out, 0, (size_t)out_size * sizeof(float), stream);
    hipMemsetAsync(d_ws, 0, (size_t)NODES * sizeof(float), stream);

    edge_scatter<<<2048, 256, 0, stream>>>(emb, cf, wts, idx, out, den, E);
    divide_kernel<<<2048, 256, 0, stream>>>(out, den, out_size / 4);
}

// Round 2
// 706.364 us; speedup vs baseline: 1.1651x; 1.1651x over previous
//
#include <hip/hip_runtime.h>
#include <cstddef>

constexpr int NODES = 100000;

__device__ __forceinline__ int rfl_i(int x) {
    return __builtin_amdgcn_readfirstlane(x);
}
__device__ __forceinline__ float rfl_f(float x) {
    return __int_as_float(__builtin_amdgcn_readfirstlane(__float_as_int(x)));
}

// ---------------- CSR build ----------------

__global__ __launch_bounds__(256) void count_kernel(
    const int* __restrict__ idx, int* __restrict__ cnt, int E)
{
    int i = blockIdx.x * blockDim.x + threadIdx.x;
    int stride = gridDim.x * blockDim.x;
    for (; i < E; i += stride) atomicAdd(&cnt[idx[i]], 1);
}

// single-block exclusive scan over NODES counts -> starts, cursor
__global__ __launch_bounds__(1024) void scan_kernel(
    const int* __restrict__ cnt, int* __restrict__ starts, int* __restrict__ cursor)
{
    __shared__ int wsum[16];
    __shared__ int running_s;
    int tid = threadIdx.x, lane = tid & 63, wv = tid >> 6;
    if (tid == 0) running_s = 0;
    __syncthreads();
    for (int base = 0; base < NODES; base += 1024) {
        int i = base + tid;
        int c = (i < NODES) ? cnt[i] : 0;
        int x = c;
        #pragma unroll
        for (int d = 1; d < 64; d <<= 1) {
            int v = __shfl_up(x, d);
            if (lane >= d) x += v;
        }
        if (lane == 63) wsum[wv] = x;
        __syncthreads();
        if (wv == 0 && lane < 16) {
            int y = wsum[lane];
            #pragma unroll
            for (int d = 1; d < 16; d <<= 1) {
                int v = __shfl_up(y, d);
                if (lane >= d) y += v;
            }
            wsum[lane] = y;
        }
        __syncthreads();
        int woff = (wv > 0) ? wsum[wv - 1] : 0;
        int r = running_s;
        int excl = r + woff + x - c;
        if (i < NODES) { starts[i] = excl; cursor[i] = excl; }
        int total = wsum[15];
        __syncthreads();                 // all reads of wsum/running_s done
        if (tid == 0) running_s = r + total;
    }
    __syncthreads();
    if (tid == 0) starts[NODES] = running_s;
}

__global__ __launch_bounds__(256) void scatter_kernel(
    const int* __restrict__ idx, const float* __restrict__ wts,
    int* __restrict__ cursor, int* __restrict__ elist,
    float* __restrict__ welist, int E)
{
    int i = blockIdx.x * blockDim.x + threadIdx.x;
    int stride = gridDim.x * blockDim.x;
    for (; i < E; i += stride) {
        int n = idx[i];
        int slot = atomicAdd(&cursor[n], 1);
        elist[slot]  = i;
        welist[slot] = wts[i];
    }
}

// ---------------- gather: one wave per node, lane = channel ----------------

__global__ __launch_bounds__(256) void gather_kernel(
    const float* __restrict__ emb, const float* __restrict__ cf,
    const int* __restrict__ starts, const int* __restrict__ elist,
    const float* __restrict__ welist, float* __restrict__ out)
{
    const int lane = threadIdx.x & 63;
    float er[16];
    #pragma unroll
    for (int f = 0; f < 16; ++f) er[f] = emb[lane * 16 + f];

    int gw = rfl_i((int)((blockIdx.x * blockDim.x + threadIdx.x) >> 6));
    int nw = (gridDim.x * blockDim.x) >> 6;

    for (int node = gw; node < NODES; node += nw) {
        int s = rfl_i(starts[node]);
        int e = rfl_i(starts[node + 1]);
        float acc = 0.f, den = 0.f;
        int p = s;
        for (; p + 4 <= e; p += 4) {
            int e0 = rfl_i(elist[p]),     e1 = rfl_i(elist[p + 1]);
            int e2 = rfl_i(elist[p + 2]), e3 = rfl_i(elist[p + 3]);
            float w0 = rfl_f(welist[p]),     w1 = rfl_f(welist[p + 1]);
            float w2 = rfl_f(welist[p + 2]), w3 = rfl_f(welist[p + 3]);
            const float* c0 = cf + (size_t)e0 * 16;
            const float* c1 = cf + (size_t)e1 * 16;
            const float* c2 = cf + (size_t)e2 * 16;
            const float* c3 = cf + (size_t)e3 * 16;
            float a0 = 0.f, a1 = 0.f, a2 = 0.f, a3 = 0.f;
            #pragma unroll
            for (int f = 0; f < 16; ++f) {
                a0 = fmaf(c0[f], er[f], a0);
                a1 = fmaf(c1[f], er[f], a1);
                a2 = fmaf(c2[f], er[f], a2);
                a3 = fmaf(c3[f], er[f], a3);
            }
            acc = fmaf(fmaxf(a0, 0.f), w0, acc);
            acc = fmaf(fmaxf(a1, 0.f), w1, acc);
            acc = fmaf(fmaxf(a2, 0.f), w2, acc);
            acc = fmaf(fmaxf(a3, 0.f), w3, acc);
            den += (w0 + w1) + (w2 + w3);
        }
        for (; p < e; ++p) {
            int e0 = rfl_i(elist[p]);
            float w0 = rfl_f(welist[p]);
            const float* c0 = cf + (size_t)e0 * 16;
            float a0 = 0.f;
            #pragma unroll
            for (int f = 0; f < 16; ++f) a0 = fmaf(c0[f], er[f], a0);
            acc = fmaf(fmaxf(a0, 0.f), w0, acc);
            den += w0;
        }
        out[(size_t)node * 64 + lane] = acc / den;
    }
}

// ---------------- fallback (round-1 atomic path) if ws too small ----------------

__global__ __launch_bounds__(256) void edge_scatter_fb(
    const float* __restrict__ emb, const float* __restrict__ cf,
    const float* __restrict__ wts, const int* __restrict__ idx,
    float* __restrict__ num, float* __restrict__ den, int E)
{
    const int lane = threadIdx.x & 63;
    float er[16];
    #pragma unroll
    for (int f = 0; f < 16; ++f) er[f] = emb[lane * 16 + f];
    int wid = rfl_i((int)((blockIdx.x * blockDim.x + threadIdx.x) >> 6));
    int nw = (gridDim.x * blockDim.x) >> 6;
    for (int e = wid; e < E; e += nw) {
        const float* c = cf + (size_t)e * 16;
        float a = 0.f;
        #pragma unroll
        for (int f = 0; f < 16; ++f) a = fmaf(c[f], er[f], a);
        float wv = wts[e];
        int n = idx[e];
        unsafeAtomicAdd(num + (size_t)n * 64 + lane, fmaxf(a, 0.f) * wv);
        if (lane == 0) unsafeAtomicAdd(den + n, wv);
    }
}

__global__ __launch_bounds__(256) void divide_fb(
    float* __restrict__ out, const float* __restrict__ den, int nvec)
{
    int i = blockIdx.x * blockDim.x + threadIdx.x;
    int stride = gridDim.x * blockDim.x;
    float4* o4 = reinterpret_cast<float4*>(out);
    for (; i < nvec; i += stride) {
        float4 v = o4[i];
        float d = den[i >> 4];
        v.x /= d; v.y /= d; v.z /= d; v.w /= d;
        o4[i] = v;
    }
}

extern "C" void kernel_launch(void* const* d_in, const int* in_sizes, int n_in,
                              void* d_out, int out_size, void* d_ws, size_t ws_size,
                              hipStream_t stream)
{
    const float* emb = (const float*)d_in[0];   // (64,16)
    const float* cf  = (const float*)d_in[1];   // (E,16)
    const float* wts = (const float*)d_in[2];   // (E,)
    const int*   idx = (const int*)d_in[3];     // (E,)
    int E = in_sizes[2];
    float* out = (float*)d_out;

    size_t need = ((size_t)3 * NODES + 2 + 2 * (size_t)E) * sizeof(int);
    if (ws_size >= need) {
        int* cnt      = (int*)d_ws;
        int* starts   = cnt + NODES;           // NODES+1
        int* cursor   = starts + NODES + 1;    // NODES
        int* elist    = cursor + NODES;        // E
        float* welist = (float*)(elist + E);   // E

        hipMemsetAsync(cnt, 0, NODES * sizeof(int), stream);
        count_kernel<<<2048, 256, 0, stream>>>(idx, cnt, E);
        scan_kernel<<<1, 1024, 0, stream>>>(cnt, starts, cursor);
        scatter_kernel<<<2048, 256, 0, stream>>>(idx, wts, cursor, elist, welist, E);
        gather_kernel<<<4096, 256, 0, stream>>>(emb, cf, starts, elist, welist, out);
    } else {
        float* den = (float*)d_ws;
        hipMemsetAsync(d_out, 0, (size_t)out_size * sizeof(float), stream);
        hipMemsetAsync(d_ws, 0, (size_t)NODES * sizeof(float), stream);
        edge_scatter_fb<<<4096, 256, 0, stream>>>(emb, cf, wts, idx, out, den, E);
        divide_fb<<<2048, 256, 0, stream>>>(out, den, out_size / 4);
    }
}